// Round 3
// baseline (12799.851 us; speedup 1.0000x reference)
//
#include <hip/hip_runtime.h>
#include <hip/hip_bf16.h>
#include <hip/hip_cooperative_groups.h>
#include <math.h>

namespace cg = cooperative_groups;

// ConvLSTMClassifier on MI355X — persistent cooperative MFMA version.
// gates[b,w,n] = bias[n] + sum_kx x[b,t,w+kx-1]*pxw[kx,n]
//              + sum_kx sum_ic h[b,w+kx-1,ic]*Bp[kx,n,ic],  n = g*128+ch.
// One cooperative kernel loops t=0..127 with grid.sync() per step.
// c lives in registers (never in memory). h ping-pongs via global bf16.
// Block: 256 thr / 4 waves; tile M=128 (w), N=256 (4 gates x 64 ch).
// Final pooling fused (shfl-reduce + atomicAdd), tiny FC kernel after.

constexpr int kB  = 64;
constexpr int kCH = 128;
constexpr int kH  = 128;
constexpr int kW  = 512;
constexpr int kNC = 10;

typedef __attribute__((ext_vector_type(8))) short short8v;
typedef __attribute__((ext_vector_type(4))) float float4v;

__device__ __forceinline__ float fsig(float v) {
    return 1.0f / (1.0f + __expf(-v));
}
__device__ __forceinline__ float ftanh(float v) {
    float e = __expf(2.0f * v);
    return 1.0f - 2.0f / (e + 1.0f);
}

// ---------------------------------------------------------------------------
// Weight pack: Bp[kx][oc][ic] bf16, pxw[kx][oc] f32, pb[oc] f32.
// Also zeroes the pooled accumulator (required every call: ws is poisoned).
// ---------------------------------------------------------------------------
__global__ __launch_bounds__(256) void pack_weights(
    const float* __restrict__ conv_w,  // [512][129][3][3]
    const float* __restrict__ conv_b,  // [512]
    short* __restrict__ Bp,            // [3][512][128]
    float* __restrict__ pxw,           // [3][512]
    float* __restrict__ pb,            // [512]
    float* __restrict__ pooled)        // [64][128]
{
    int idx = blockIdx.x * 256 + threadIdx.x;
    if (idx < 3 * 512 * 128) {
        int ic = idx & 127;
        int oc = (idx >> 7) & 511;
        int kx = idx >> 16;
        float v = conv_w[((oc * 129 + 1 + ic) * 3 + 1) * 3 + kx];
        __hip_bfloat16 hv = __float2bfloat16(v);
        Bp[idx] = *reinterpret_cast<short*>(&hv);
    }
    if (idx < 3 * 512) {
        int oc = idx & 511, kx = idx >> 9;
        pxw[idx] = conv_w[((oc * 129 + 0) * 3 + 1) * 3 + kx];
    }
    if (idx < 512) pb[idx] = conv_b[idx];
    if (idx < kB * kCH) pooled[idx] = 0.0f;
}

// ---------------------------------------------------------------------------
// Persistent LSTM. grid = (4 wtiles, 2 cht, 64 b) = 512 blocks, 256 thr.
// 2 blocks/CU co-resident (launch_bounds(256,2) caps VGPR at 256).
// ---------------------------------------------------------------------------
__global__ __launch_bounds__(256, 2) void lstm_persist(
    const float* __restrict__ x,          // [B][1][H][W]
    const short* __restrict__ Bp,         // [3][512][128]
    const float* __restrict__ pxw,        // [3][512]
    const float* __restrict__ pb,         // [512]
    __hip_bfloat16* __restrict__ hA,      // [B][W][CH]
    __hip_bfloat16* __restrict__ hB,      // [B][W][CH]
    float* __restrict__ pooled)           // [B][CH] (pre-zeroed)
{
    cg::grid_group gg = cg::this_grid();

    __shared__ alignas(16) short Alds[130 * 128];  // rows w0-1..w0+128, swizzled
    __shared__ float xs[130];

    const int tid  = threadIdx.x;
    const int lane = tid & 63;
    const int wave = tid >> 6;
    const int w0   = blockIdx.x * 128;
    const int cht  = blockIdx.y;
    const int b    = blockIdx.z;

    const int ncol = lane & 15;
    const int krow = lane >> 4;
    const int ch16 = cht * 64 + wave * 16;
    const int chg  = ch16 + ncol;

    // hoist per-lane weights: bias + x-channel conv weights
    float wxk[4][3], bia[4];
#pragma unroll
    for (int g = 0; g < 4; ++g) {
        bia[g] = pb[g * 128 + chg];
#pragma unroll
        for (int kx = 0; kx < 3; ++kx)
            wxk[g][kx] = pxw[kx * 512 + g * 128 + chg];
    }

    float creg[8][4];  // cell state, in registers for the whole run
#pragma unroll
    for (int mf = 0; mf < 8; ++mf)
#pragma unroll
        for (int r = 0; r < 4; ++r)
            creg[mf][r] = 0.0f;
    float psum = 0.0f;

    const float* xb = x + (size_t)b * kH * kW;
    const size_t hrow_base = (size_t)b * kW * kCH;

    for (int t = 0; t < kH; ++t) {
        const __hip_bfloat16* hread = (t & 1) ? hA : hB;
        __hip_bfloat16* hwrite      = (t & 1) ? hB : hA;

        if (t > 0) gg.sync();  // all writes of step t-1 visible

        // stage x strip
        for (int s = tid; s < 130; s += 256) {
            int w = w0 - 1 + s;
            xs[s] = (w >= 0 && w < kW) ? xb[t * kW + w] : 0.0f;
        }

        float4v acc[8][4];  // [mfrag][gate]
#pragma unroll
        for (int mf = 0; mf < 8; ++mf)
#pragma unroll
            for (int g = 0; g < 4; ++g)
                acc[mf][g] = float4v{0.0f, 0.0f, 0.0f, 0.0f};

        if (t > 0) {
            // stage h slab (130 rows x 128 ch bf16), XOR-swizzled 16B slots
            for (int s = tid; s < 130 * 16; s += 256) {
                int row = s >> 4, col = s & 15;
                int w = w0 - 1 + row;
                short8v v = {0, 0, 0, 0, 0, 0, 0, 0};
                if (w >= 0 && w < kW) {
                    v = *reinterpret_cast<const short8v*>(
                        reinterpret_cast<const short*>(hread) +
                        (hrow_base + (size_t)w * kCH + col * 8));
                }
                int slot = col ^ (row & 7);
                *reinterpret_cast<short8v*>(Alds + row * 128 + slot * 8) = v;
            }
            __syncthreads();

#pragma unroll
            for (int kx = 0; kx < 3; ++kx) {
#pragma unroll
                for (int ks = 0; ks < 4; ++ks) {
                    short8v bfr[4];
#pragma unroll
                    for (int g = 0; g < 4; ++g) {
                        int n = g * 128 + chg;
                        bfr[g] = *reinterpret_cast<const short8v*>(
                            Bp + (((size_t)kx * 512 + n) * 128 + ks * 32 + krow * 8));
                    }
                    const int slot = (ks * 4 + krow) ^ ((ncol + kx) & 7);
#pragma unroll
                    for (int mf = 0; mf < 8; ++mf) {
                        int srow = mf * 16 + ncol + kx;
                        short8v afr = *reinterpret_cast<const short8v*>(
                            Alds + srow * 128 + slot * 8);
#pragma unroll
                        for (int g = 0; g < 4; ++g)
                            acc[mf][g] = __builtin_amdgcn_mfma_f32_16x16x32_bf16(
                                afr, bfr[g], acc[mf][g], 0, 0, 0);
                    }
                }
            }
        } else {
            __syncthreads();  // xs visibility
        }

        // epilogue: gates + state update; h write (or pooling at final step)
#pragma unroll
        for (int mf = 0; mf < 8; ++mf) {
#pragma unroll
            for (int r = 0; r < 4; ++r) {
                int m = mf * 16 + krow * 4 + r;
                float xm = xs[m], xc = xs[m + 1], xp = xs[m + 2];
                float v0 = acc[mf][0][r] + bia[0] + xm * wxk[0][0] + xc * wxk[0][1] + xp * wxk[0][2];
                float v1 = acc[mf][1][r] + bia[1] + xm * wxk[1][0] + xc * wxk[1][1] + xp * wxk[1][2];
                float v2 = acc[mf][2][r] + bia[2] + xm * wxk[2][0] + xc * wxk[2][1] + xp * wxk[2][2];
                float v3 = acc[mf][3][r] + bia[3] + xm * wxk[3][0] + xc * wxk[3][1] + xp * wxk[3][2];
                float si = fsig(v0);
                float sf = fsig(v1);
                float tg = ftanh(v2);
                float so = fsig(v3);
                float cn = sf * creg[mf][r] + si * tg;
                float hn = so * ftanh(cn);
                creg[mf][r] = cn;
                if (t < kH - 1) {
                    hwrite[hrow_base + (size_t)(w0 + m) * kCH + chg] = __float2bfloat16(hn);
                } else {
                    psum += hn;
                }
            }
        }
    }

    // pooling: reduce over krow lanes (same ch, different rows), then atomic
    psum += __shfl_xor(psum, 16, 64);
    psum += __shfl_xor(psum, 32, 64);
    if (krow == 0) atomicAdd(&pooled[b * kCH + chg], psum);
}

// ---------------------------------------------------------------------------
// Final FC from pooled sums. grid = B, block = 64.
// ---------------------------------------------------------------------------
__global__ __launch_bounds__(64) void fc_final(
    const float* __restrict__ pooled,  // [B][CH] raw sums over W
    const float* __restrict__ fc_w,    // [NC][CH]
    const float* __restrict__ fc_b,    // [NC]
    float* __restrict__ out)           // [B][NC]
{
    int b = blockIdx.x, nc = threadIdx.x;
    if (nc < kNC) {
        float s = 0.0f;
        for (int k = 0; k < kCH; ++k)
            s = fmaf(pooled[b * kCH + k], fc_w[nc * kCH + k], s);
        out[b * kNC + nc] = fc_b[nc] + s * (1.0f / kW);
    }
}

// ===========================================================================
// Fallback path (round-2 proven): multi-launch steps with c in global.
// Used only if the cooperative launch is rejected.
// ===========================================================================
template <bool FIRST>
__global__ __launch_bounds__(256, 4) void lstm_step(
    const float* __restrict__ x,
    const short* __restrict__ Bp,
    const float* __restrict__ pxw,
    const float* __restrict__ pb,
    const __hip_bfloat16* __restrict__ hprev,
    __hip_bfloat16* __restrict__ hnext,
    float* __restrict__ c,
    int t)
{
    __shared__ alignas(16) short Alds[66 * 128];
    __shared__ float xs[66];

    const int tid  = threadIdx.x;
    const int lane = tid & 63;
    const int wave = tid >> 6;
    const int w0   = blockIdx.x * 64;
    const int cht  = blockIdx.y;
    const int b    = blockIdx.z;

    for (int s = tid; s < 66; s += 256) {
        int w = w0 - 1 + s;
        xs[s] = (w >= 0 && w < kW) ? x[((size_t)b * kH + t) * kW + w] : 0.0f;
    }
    if (!FIRST) {
        for (int s = tid; s < 66 * 16; s += 256) {
            int row = s >> 4, col = s & 15;
            int w = w0 - 1 + row;
            short8v v = {0, 0, 0, 0, 0, 0, 0, 0};
            if (w >= 0 && w < kW) {
                v = *reinterpret_cast<const short8v*>(
                    reinterpret_cast<const short*>(hprev) +
                    (((size_t)b * kW + w) * kCH + col * 8));
            }
            int slot = col ^ (row & 7);
            *reinterpret_cast<short8v*>(Alds + row * 128 + slot * 8) = v;
        }
    }
    __syncthreads();

    float4v acc[4][4];
#pragma unroll
    for (int mf = 0; mf < 4; ++mf)
#pragma unroll
        for (int g = 0; g < 4; ++g)
            acc[mf][g] = float4v{0.0f, 0.0f, 0.0f, 0.0f};

    const int ncol = lane & 15;
    const int krow = lane >> 4;
    const int ch16 = cht * 64 + wave * 16;

    if (!FIRST) {
#pragma unroll
        for (int kx = 0; kx < 3; ++kx) {
#pragma unroll
            for (int ks = 0; ks < 4; ++ks) {
                short8v bfr[4];
#pragma unroll
                for (int g = 0; g < 4; ++g) {
                    int n = g * 128 + ch16 + ncol;
                    bfr[g] = *reinterpret_cast<const short8v*>(
                        Bp + (((size_t)kx * 512 + n) * 128 + ks * 32 + krow * 8));
                }
#pragma unroll
                for (int mf = 0; mf < 4; ++mf) {
                    int srow = mf * 16 + ncol + kx;
                    int slot = (ks * 4 + krow) ^ (srow & 7);
                    short8v afr = *reinterpret_cast<const short8v*>(
                        Alds + srow * 128 + slot * 8);
#pragma unroll
                    for (int g = 0; g < 4; ++g)
                        acc[mf][g] = __builtin_amdgcn_mfma_f32_16x16x32_bf16(
                            afr, bfr[g], acc[mf][g], 0, 0, 0);
                }
            }
        }
    }

    const int chg = ch16 + ncol;
    float wxk[4][3], bia[4];
#pragma unroll
    for (int g = 0; g < 4; ++g) {
        bia[g] = pb[g * 128 + chg];
#pragma unroll
        for (int kx = 0; kx < 3; ++kx)
            wxk[g][kx] = pxw[kx * 512 + g * 128 + chg];
    }

#pragma unroll
    for (int mf = 0; mf < 4; ++mf) {
#pragma unroll
        for (int r = 0; r < 4; ++r) {
            int m = mf * 16 + krow * 4 + r;
            float xm = xs[m], xc = xs[m + 1], xp = xs[m + 2];
            float v[4];
#pragma unroll
            for (int g = 0; g < 4; ++g)
                v[g] = acc[mf][g][r] + bia[g]
                     + xm * wxk[g][0] + xc * wxk[g][1] + xp * wxk[g][2];
            size_t idx = ((size_t)b * kW + (w0 + m)) * kCH + chg;
            float cprev = FIRST ? 0.0f : c[idx];
            float si = fsig(v[0]);
            float sf = fsig(v[1]);
            float tg = ftanh(v[2]);
            float so = fsig(v[3]);
            float cn = sf * cprev + si * tg;
            float hn = so * ftanh(cn);
            c[idx] = cn;
            hnext[idx] = __float2bfloat16(hn);
        }
    }
}

__global__ __launch_bounds__(256) void pool_fc(
    const __hip_bfloat16* __restrict__ h,
    const float* __restrict__ fc_w,
    const float* __restrict__ fc_b,
    float* __restrict__ out)
{
    __shared__ float part[256];
    __shared__ float pooled_s[kCH];
    const int b = blockIdx.x, tid = threadIdx.x;
    const int ch = tid & 127, half = tid >> 7;
    float s = 0.0f;
    for (int w = half * 256; w < half * 256 + 256; ++w)
        s += __bfloat162float(h[((size_t)b * kW + w) * kCH + ch]);
    part[tid] = s;
    __syncthreads();
    if (tid < kCH) pooled_s[tid] = (part[tid] + part[tid + 128]) * (1.0f / kW);
    __syncthreads();
    if (tid < kNC) {
        float a = fc_b[tid];
        for (int k = 0; k < kCH; ++k)
            a = fmaf(pooled_s[k], fc_w[tid * kCH + k], a);
        out[b * kNC + tid] = a;
    }
}

// ---------------------------------------------------------------------------
extern "C" void kernel_launch(void* const* d_in, const int* in_sizes, int n_in,
                              void* d_out, int out_size, void* d_ws, size_t ws_size,
                              hipStream_t stream) {
    const float* x      = (const float*)d_in[0];
    const float* conv_w = (const float*)d_in[1];
    const float* conv_b = (const float*)d_in[2];
    const float* fc_w   = (const float*)d_in[3];
    const float* fc_b   = (const float*)d_in[4];
    float* out = (float*)d_out;

    const size_t stateN = (size_t)kB * kW * kCH;  // 4,194,304
    float* c            = (float*)d_ws;                    // fallback only
    __hip_bfloat16* hA  = (__hip_bfloat16*)(c + stateN);
    __hip_bfloat16* hB  = hA + stateN;
    short* Bp           = (short*)(hB + stateN);
    float* pxw          = (float*)(Bp + 3 * 512 * 128);
    float* pb           = pxw + 3 * 512;
    float* pooled       = pb + 512;  // [64][128]

    pack_weights<<<768, 256, 0, stream>>>(conv_w, conv_b, Bp, pxw, pb, pooled);

    void* args[] = {(void*)&x, (void*)&Bp, (void*)&pxw, (void*)&pb,
                    (void*)&hA, (void*)&hB, (void*)&pooled};
    hipError_t err = hipLaunchCooperativeKernel(
        (const void*)lstm_persist, dim3(4, 2, 64), dim3(256), args, 0, stream);

    if (err == hipSuccess) {
        fc_final<<<kB, 64, 0, stream>>>(pooled, fc_w, fc_b, out);
    } else {
        // fallback: proven multi-launch path
        dim3 grid(kW / 64, 2, kB);
        dim3 block(256);
        lstm_step<true><<<grid, block, 0, stream>>>(x, Bp, pxw, pb, hA, hB, c, 0);
        for (int t = 1; t < kH; ++t) {
            __hip_bfloat16* hp = (t & 1) ? hB : hA;
            __hip_bfloat16* hn = (t & 1) ? hA : hB;
            lstm_step<false><<<grid, block, 0, stream>>>(x, Bp, pxw, pb, hp, hn, c, t);
        }
        pool_fc<<<kB, 256, 0, stream>>>(hA, fc_w, fc_b, out);
    }
}

// Round 4
// 4623.527 us; speedup vs baseline: 2.7684x; 2.7684x over previous
//
#include <hip/hip_runtime.h>
#include <hip/hip_bf16.h>
#include <math.h>

// ConvLSTMClassifier on MI355X — 2-steps-per-launch fused MFMA version.
// gates[b,w,n] = bias[n] + sum_kx x[b,t,w+kx-1]*pxw[kx,n]
//              + sum_kx sum_ic h[b,w+kx-1,ic]*Bp[kx,n,ic],  n = g*128+ch.
// Each launch runs steps (t, t+1). Block owns M=128 w-rows x ALL 512 n.
// Step t computes a 130-row halo range; h(t)->LDS S1, c(t)->LDS cbuf
// (neither touches global). Step t+1 computes 128 owned rows -> global.
// grid (4 wtiles, 64 b) = 256 blocks (1/CU), 512 thr = 8 waves.
// Final launch fuses mean-pooling (shfl + atomicAdd); tiny FC after.

constexpr int kB  = 64;
constexpr int kCH = 128;
constexpr int kH  = 128;
constexpr int kW  = 512;
constexpr int kNC = 10;

typedef __attribute__((ext_vector_type(8))) short short8v;
typedef __attribute__((ext_vector_type(4))) float float4v;

__device__ __forceinline__ float fsig(float v) {
    return 1.0f / (1.0f + __expf(-v));
}
__device__ __forceinline__ float ftanh(float v) {
    float e = __expf(2.0f * v);
    return 1.0f - 2.0f / (e + 1.0f);
}

// ---------------------------------------------------------------------------
// Weight pack: Bp[kx][oc][ic] bf16, pxw[kx][oc] f32, pb[oc] f32.
// Also zeroes the pooled accumulator (ws is poisoned before timing).
// ---------------------------------------------------------------------------
__global__ __launch_bounds__(256) void pack_weights(
    const float* __restrict__ conv_w,  // [512][129][3][3]
    const float* __restrict__ conv_b,  // [512]
    short* __restrict__ Bp,            // [3][512][128]
    float* __restrict__ pxw,           // [3][512]
    float* __restrict__ pb,            // [512]
    float* __restrict__ pooled)        // [64][128]
{
    int idx = blockIdx.x * 256 + threadIdx.x;
    if (idx < 3 * 512 * 128) {
        int ic = idx & 127;
        int oc = (idx >> 7) & 511;
        int kx = idx >> 16;
        float v = conv_w[((oc * 129 + 1 + ic) * 3 + 1) * 3 + kx];
        __hip_bfloat16 hv = __float2bfloat16(v);
        Bp[idx] = *reinterpret_cast<short*>(&hv);
    }
    if (idx < 3 * 512) {
        int oc = idx & 511, kx = idx >> 9;
        pxw[idx] = conv_w[((oc * 129 + 0) * 3 + 1) * 3 + kx];
    }
    if (idx < 512) pb[idx] = conv_b[idx];
    if (idx < kB * kCH) pooled[idx] = 0.0f;
}

// ---------------------------------------------------------------------------
// GEMM phase macro: NMF M-fragments starting at MFBASE, from LDS slab SLAB.
// Output rows m = MFBASE*16 .. +NMF*16-1; slab row for output m at tap kx is
// m + kx (slab row s holds h[w_base + s], w_base = out_w_base - 1).
// ---------------------------------------------------------------------------
#define GEMM_PHASE(SLAB, MFBASE, NMF, ACC)                                     \
    _Pragma("unroll")                                                          \
    for (int kx = 0; kx < 3; ++kx) {                                           \
        _Pragma("unroll")                                                      \
        for (int ks = 0; ks < 4; ++ks) {                                       \
            short8v bfr[4];                                                    \
            _Pragma("unroll")                                                  \
            for (int g = 0; g < 4; ++g)                                        \
                bfr[g] = *reinterpret_cast<const short8v*>(                    \
                    Bp + ((size_t)(kx * 512 + g * 128 + ch16 + ncol) * 128 +   \
                          ks * 32 + krow * 8));                                \
            _Pragma("unroll")                                                  \
            for (int i = 0; i < (NMF); ++i) {                                  \
                int srow = ((MFBASE) + i) * 16 + ncol + kx;                    \
                int slot = (ks * 4 + krow) ^ (srow & 7);                       \
                short8v afr = *reinterpret_cast<const short8v*>(               \
                    (SLAB) + srow * 128 + slot * 8);                           \
                _Pragma("unroll")                                              \
                for (int g = 0; g < 4; ++g)                                    \
                    (ACC)[i][g] = __builtin_amdgcn_mfma_f32_16x16x32_bf16(     \
                        afr, bfr[g], (ACC)[i][g], 0, 0, 0);                    \
            }                                                                  \
        }                                                                      \
    }

// Step-t epilogue: rows m (output w = w0-1+m), m < 130 valid.
// h -> S1 (swizzled, 0 at w-boundaries), c -> cbuf. cprev from global cIn.
#define EPI_T(MFBASE, NMF, ACC)                                                \
    _Pragma("unroll")                                                          \
    for (int i = 0; i < (NMF); ++i) {                                          \
        _Pragma("unroll")                                                      \
        for (int r = 0; r < 4; ++r) {                                          \
            int m = ((MFBASE) + i) * 16 + krow * 4 + r;                        \
            if (m < 130) {                                                     \
                int w = w0 - 1 + m;                                            \
                bool inb = (w >= 0) && (w < kW);                               \
                float xm = xs0[m], xc = xs0[m + 1], xp = xs0[m + 2];           \
                float v0 = (ACC)[i][0][r] + bia[0] + xm * wxk[0][0] + xc * wxk[0][1] + xp * wxk[0][2]; \
                float v1 = (ACC)[i][1][r] + bia[1] + xm * wxk[1][0] + xc * wxk[1][1] + xp * wxk[1][2]; \
                float v2 = (ACC)[i][2][r] + bia[2] + xm * wxk[2][0] + xc * wxk[2][1] + xp * wxk[2][2]; \
                float v3 = (ACC)[i][3][r] + bia[3] + xm * wxk[3][0] + xc * wxk[3][1] + xp * wxk[3][2]; \
                float cprev = 0.0f;                                            \
                if (!FIRST && inb) cprev = cIn[gbase + (size_t)w * kCH + ch];  \
                float si = fsig(v0), sf = fsig(v1);                            \
                float tg = ftanh(v2), so = fsig(v3);                           \
                float cn = sf * cprev + si * tg;                               \
                float hn = so * ftanh(cn);                                     \
                cbuf[m * 136 + ch] = cn;                                       \
                __hip_bfloat16 hv = __float2bfloat16(inb ? hn : 0.0f);         \
                S1[m * 128 + (((ch >> 3) ^ (m & 7)) * 8) + (ch & 7)] =         \
                    *reinterpret_cast<short*>(&hv);                            \
            }                                                                  \
        }                                                                      \
    }

// Step-(t+1) epilogue: rows m (output w = w0+m, always in-bounds).
// cprev from cbuf row m+1. Writes global (or pools if LAST).
#define EPI_U(MFBASE, NMF, ACC)                                                \
    _Pragma("unroll")                                                          \
    for (int i = 0; i < (NMF); ++i) {                                          \
        _Pragma("unroll")                                                      \
        for (int r = 0; r < 4; ++r) {                                          \
            int m = ((MFBASE) + i) * 16 + krow * 4 + r;                        \
            int w = w0 + m;                                                    \
            float xm = xs1[m], xc = xs1[m + 1], xp = xs1[m + 2];               \
            float v0 = (ACC)[i][0][r] + bia[0] + xm * wxk[0][0] + xc * wxk[0][1] + xp * wxk[0][2]; \
            float v1 = (ACC)[i][1][r] + bia[1] + xm * wxk[1][0] + xc * wxk[1][1] + xp * wxk[1][2]; \
            float v2 = (ACC)[i][2][r] + bia[2] + xm * wxk[2][0] + xc * wxk[2][1] + xp * wxk[2][2]; \
            float v3 = (ACC)[i][3][r] + bia[3] + xm * wxk[3][0] + xc * wxk[3][1] + xp * wxk[3][2]; \
            float cprev = cbuf[(m + 1) * 136 + ch];                            \
            float si = fsig(v0), sf = fsig(v1);                                \
            float tg = ftanh(v2), so = fsig(v3);                               \
            float cn = sf * cprev + si * tg;                                   \
            float hn = so * ftanh(cn);                                         \
            if (LAST) {                                                        \
                psum += hn;                                                    \
            } else {                                                           \
                size_t gi = gbase + (size_t)w * kCH + ch;                      \
                hOut[gi] = __float2bfloat16(hn);                               \
                cOut[gi] = cn;                                                 \
            }                                                                  \
        }                                                                      \
    }

// ---------------------------------------------------------------------------
template <bool FIRST, bool LAST>
__global__ __launch_bounds__(512, 2) void lstm2(
    const float* __restrict__ x,          // [B][1][H][W]
    const short* __restrict__ Bp,         // [3][512][128]
    const float* __restrict__ pxw,        // [3][512]
    const float* __restrict__ pb,         // [512]
    const __hip_bfloat16* __restrict__ hIn,   // [B][W][CH]
    __hip_bfloat16* __restrict__ hOut,        // [B][W][CH]
    const float* __restrict__ cIn,            // [B][W][CH]
    float* __restrict__ cOut,                 // [B][W][CH]
    float* __restrict__ pooled,               // [B][CH]
    int t0)
{
    __shared__ alignas(16) short S0[146 * 128];   // h(t-1): rows w0-2 .. (swz)
    __shared__ alignas(16) short S1[130 * 128];   // h(t):   rows w0-1 .. (swz)
    __shared__ float cbuf[130 * 136];             // c(t), padded stride
    __shared__ float xs0[132];
    __shared__ float xs1[132];

    const int tid  = threadIdx.x;
    const int lane = tid & 63;
    const int wave = tid >> 6;
    const int w0   = blockIdx.x * 128;
    const int b    = blockIdx.y;

    const int ncol = lane & 15;
    const int krow = lane >> 4;
    const int ch16 = wave * 16;
    const int ch   = ch16 + ncol;

    // per-lane constants: bias + x-channel conv weights
    float wxk[4][3], bia[4];
#pragma unroll
    for (int g = 0; g < 4; ++g) {
        bia[g] = pb[g * 128 + ch];
#pragma unroll
        for (int kx = 0; kx < 3; ++kx)
            wxk[g][kx] = pxw[kx * 512 + g * 128 + ch];
    }

    const float* xrow0 = x + ((size_t)b * kH + t0) * kW;
    const float* xrow1 = xrow0 + kW;
    const size_t gbase = (size_t)b * kW * kCH;

    // ---- staging ----
    for (int s = tid; s < 132; s += 512) {
        int wa = w0 - 2 + s;
        xs0[s] = (wa >= 0 && wa < kW) ? xrow0[wa] : 0.0f;
        int wb = w0 - 1 + s;
        xs1[s] = (s < 130 && wb >= 0 && wb < kW) ? xrow1[wb] : 0.0f;
    }
    if (!FIRST) {
        for (int s = tid; s < 146 * 16; s += 512) {
            int row = s >> 4, col = s & 15;
            int w = w0 - 2 + row;
            short8v v = {0, 0, 0, 0, 0, 0, 0, 0};
            if (w >= 0 && w < kW)
                v = *reinterpret_cast<const short8v*>(
                    reinterpret_cast<const short*>(hIn) +
                    (gbase + (size_t)w * kCH + col * 8));
            *reinterpret_cast<short8v*>(
                S0 + row * 128 + (col ^ (row & 7)) * 8) = v;
        }
    }
    __syncthreads();

    float psum = 0.0f;

    // ---- step t: 130 output rows (9 frags), two phases (5+4) ----
    {
        float4v accA[5][4];
#pragma unroll
        for (int i = 0; i < 5; ++i)
#pragma unroll
            for (int g = 0; g < 4; ++g) accA[i][g] = float4v{0.f, 0.f, 0.f, 0.f};
        if (!FIRST) { GEMM_PHASE(S0, 0, 5, accA) }
        EPI_T(0, 5, accA)
    }
    {
        float4v accB[4][4];
#pragma unroll
        for (int i = 0; i < 4; ++i)
#pragma unroll
            for (int g = 0; g < 4; ++g) accB[i][g] = float4v{0.f, 0.f, 0.f, 0.f};
        if (!FIRST) { GEMM_PHASE(S0, 5, 4, accB) }
        EPI_T(5, 4, accB)
    }
    __syncthreads();  // S1 + cbuf complete

    // ---- step t+1: 128 owned rows (8 frags), two phases (4+4) ----
    {
        float4v accC[4][4];
#pragma unroll
        for (int i = 0; i < 4; ++i)
#pragma unroll
            for (int g = 0; g < 4; ++g) accC[i][g] = float4v{0.f, 0.f, 0.f, 0.f};
        GEMM_PHASE(S1, 0, 4, accC)
        EPI_U(0, 4, accC)
    }
    {
        float4v accD[4][4];
#pragma unroll
        for (int i = 0; i < 4; ++i)
#pragma unroll
            for (int g = 0; g < 4; ++g) accD[i][g] = float4v{0.f, 0.f, 0.f, 0.f};
        GEMM_PHASE(S1, 4, 4, accD)
        EPI_U(4, 4, accD)
    }

    if (LAST) {
        psum += __shfl_xor(psum, 16, 64);
        psum += __shfl_xor(psum, 32, 64);
        if (krow == 0) atomicAdd(&pooled[b * kCH + ch], psum);
    }
}

// ---------------------------------------------------------------------------
// Final FC from pooled sums. grid = B, block = 64.
// ---------------------------------------------------------------------------
__global__ __launch_bounds__(64) void fc_final(
    const float* __restrict__ pooled,  // [B][CH] raw sums over W
    const float* __restrict__ fc_w,    // [NC][CH]
    const float* __restrict__ fc_b,    // [NC]
    float* __restrict__ out)           // [B][NC]
{
    int b = blockIdx.x, nc = threadIdx.x;
    if (nc < kNC) {
        float s = 0.0f;
        for (int k = 0; k < kCH; ++k)
            s = fmaf(pooled[b * kCH + k], fc_w[nc * kCH + k], s);
        out[b * kNC + nc] = fc_b[nc] + s * (1.0f / kW);
    }
}

// ---------------------------------------------------------------------------
extern "C" void kernel_launch(void* const* d_in, const int* in_sizes, int n_in,
                              void* d_out, int out_size, void* d_ws, size_t ws_size,
                              hipStream_t stream) {
    const float* x      = (const float*)d_in[0];
    const float* conv_w = (const float*)d_in[1];
    const float* conv_b = (const float*)d_in[2];
    const float* fc_w   = (const float*)d_in[3];
    const float* fc_b   = (const float*)d_in[4];
    float* out = (float*)d_out;

    const size_t stateN = (size_t)kB * kW * kCH;  // 4,194,304
    float* cA           = (float*)d_ws;
    float* cB           = cA + stateN;
    __hip_bfloat16* hA  = (__hip_bfloat16*)(cB + stateN);
    __hip_bfloat16* hB  = hA + stateN;
    short* Bp           = (short*)(hB + stateN);
    float* pxw          = (float*)(Bp + 3 * 512 * 128);
    float* pb           = pxw + 3 * 512;
    float* pooled       = pb + 512;  // [64][128]

    pack_weights<<<768, 256, 0, stream>>>(conv_w, conv_b, Bp, pxw, pb, pooled);

    dim3 grid(kW / 128, kB);
    dim3 block(512);
    // launch k handles steps (2k, 2k+1); writes h(2k+1)/c(2k+1) to
    // out(k) = k even ? A : B; reads out(k-1).
    lstm2<true, false><<<grid, block, 0, stream>>>(
        x, Bp, pxw, pb, hB, hA, cB, cA, pooled, 0);
    for (int k = 1; k < 63; ++k) {
        __hip_bfloat16* hi = (k & 1) ? hA : hB;
        __hip_bfloat16* ho = (k & 1) ? hB : hA;
        float* ci = (k & 1) ? cA : cB;
        float* co = (k & 1) ? cB : cA;
        lstm2<false, false><<<grid, block, 0, stream>>>(
            x, Bp, pxw, pb, hi, ho, ci, co, pooled, 2 * k);
    }
    // k = 63 (odd): reads A-buffers; outputs pooled only.
    lstm2<false, true><<<grid, block, 0, stream>>>(
        x, Bp, pxw, pb, hA, hB, cA, cB, pooled, 126);

    fc_final<<<kB, 64, 0, stream>>>(pooled, fc_w, fc_b, out);
}